// Round 3
// baseline (261.948 us; speedup 1.0000x reference)
//
#include <hip/hip_runtime.h>

typedef unsigned short u16;
typedef unsigned int u32;

#define LDSW 68  // padded fp32 row stride: 16B-aligned float4 rows

__device__ __forceinline__ float bflo(u32 v){ union{float f;u32 i;}c; c.i = v<<16; return c.f; }
__device__ __forceinline__ float bfhi(u32 v){ union{float f;u32 i;}c; c.i = v & 0xFFFF0000u; return c.f; }
__device__ __forceinline__ u16 f2bf(float f){
    union{float f;u32 i;}c; c.f = f;
    u32 i = c.i;
    return (u16)((i + 0x7FFFu + ((i>>16)&1u)) >> 16);  // RNE
}

// load 16 contiguous fp32 from global into dst (both 16B-aligned)
__device__ __forceinline__ void load16g(const float* __restrict__ g, float* __restrict__ dst){
    const float4* p = (const float4*)g;
    float4 a = p[0], b = p[1], c = p[2], d = p[3];
    *(float4*)&dst[0]  = a;
    *(float4*)&dst[4]  = b;
    *(float4*)&dst[8]  = c;
    *(float4*)&dst[12] = d;
}

// acc[j] += sum_d xrow[d] * wc[d*LDSW + j], j<16 (wc already offset by c0)
__device__ __forceinline__ void mm_row16(const float* __restrict__ xrow,
                                         const float* __restrict__ wc,
                                         float* __restrict__ acc){
    #pragma unroll
    for (int d = 0; d < 64; d += 4) {
        float4 xv = *(const float4*)&xrow[d];
        #pragma unroll
        for (int dd = 0; dd < 4; ++dd) {
            const float xf = (dd==0)?xv.x:((dd==1)?xv.y:((dd==2)?xv.z:xv.w));
            const float* wr = wc + (d+dd)*LDSW;
            #pragma unroll
            for (int j = 0; j < 16; j += 4) {
                float4 wv = *(const float4*)&wr[j];
                acc[j+0] = fmaf(xf, wv.x, acc[j+0]);
                acc[j+1] = fmaf(xf, wv.y, acc[j+1]);
                acc[j+2] = fmaf(xf, wv.z, acc[j+2]);
                acc[j+3] = fmaf(xf, wv.w, acc[j+3]);
            }
        }
    }
}

__global__ __launch_bounds__(256, 2) void attn_fused_kernel(
    const float* __restrict__ x, const float* __restrict__ pos, const float* __restrict__ strength,
    const int* __restrict__ embed_id,
    const float* __restrict__ Wq, const float* __restrict__ Wk,
    const float* __restrict__ pW1, const float* __restrict__ pb1,
    const float* __restrict__ pW2, const float* __restrict__ pb2,
    const float* __restrict__ hW, const float* __restrict__ hb,
    const float* __restrict__ gate, const float* __restrict__ embeds,
    const float* __restrict__ oW, const float* __restrict__ ob,
    const float* __restrict__ sW, const float* __restrict__ sb,
    float* __restrict__ out)
{
    __shared__ __align__(16) float xs[64*LDSW];   // x tile fp32; reused as context after attention
    __shared__ __align__(16) float ws[64*LDSW];   // weight buffer (Wq -> Wk -> E^T -> out_W)
    __shared__ __align__(16) float ksh[64*64];    // k in fp32 (row-broadcast access, no pad needed)
    __shared__ __align__(16) u16  vsh[64*64];     // v in bf16
    __shared__ __align__(16) float t_lds[4][64];
    __shared__ __align__(16) float pattn[4][64];
    __shared__ __align__(16) float sp[4][64];
    __shared__ __align__(16) float s64[64];

    const int t  = threadIdx.x;
    const int b  = blockIdx.x;
    const int n  = t >> 2;       // row 0..63
    const int hq = t & 3;        // head / col-quarter
    const int c0 = hq << 4;      // column base

    // ---- Phase 1: stage x, strength partials, pos MLP ----
    load16g(x + ((size_t)b*64 + n)*64 + c0, &xs[n*LDSW + c0]);

    {   // s64[d] = strength @ str_W[:,d]; 4 partial slices of 128
        const int d = t & 63, part = t >> 6;
        const float* w = sW + part*128*64 + d;
        const float* s = strength + part*128;
        float acc = 0.f;
        #pragma unroll 8
        for (int i = 0; i < 128; ++i) acc = fmaf(s[i], w[i*64], acc);
        sp[part][d] = acc;
    }

    if (t < 64) {  // pos MLP: p = relu(pos@W1+b1)@W2+b2 ; t[n,h] = p . head_W[:,h]
        float pv[4], h1[4], p8[8];
        const float* gp = pos + ((size_t)b*64 + t)*4;
        #pragma unroll
        for (int i = 0; i < 4; ++i) pv[i] = gp[i];
        #pragma unroll
        for (int j = 0; j < 4; ++j){
            float a = pb1[j];
            #pragma unroll
            for (int i = 0; i < 4; ++i) a = fmaf(pv[i], pW1[i*4+j], a);
            h1[j] = fmaxf(a, 0.f);
        }
        #pragma unroll
        for (int f = 0; f < 8; ++f){
            float a = pb2[f];
            #pragma unroll
            for (int j = 0; j < 4; ++j) a = fmaf(h1[j], pW2[j*8+f], a);
            p8[f] = a;
        }
        #pragma unroll
        for (int h = 0; h < 4; ++h){
            float a = 0.f;
            #pragma unroll
            for (int f = 0; f < 8; ++f) a = fmaf(p8[f], hW[f*4+h], a);
            t_lds[h][t] = a;
        }
    }
    __syncthreads();

    // ---- Phase 2: s64 reduce; pos_attn[h][k] = softmax_k(-t[k,h]) (q-independent!); load Wq ----
    if (t < 64) s64[t] = sp[0][t] + sp[1][t] + sp[2][t] + sp[3][t] + sb[t];
    {
        const int h = t >> 6, k = t & 63;   // wave h handles head h, lane = k
        float v0 = -t_lds[h][k];
        float m = v0;
        #pragma unroll
        for (int off = 32; off; off >>= 1) m = fmaxf(m, __shfl_xor(m, off));
        float e = __expf(v0 - m);
        float ssum = e;
        #pragma unroll
        for (int off = 32; off; off >>= 1) ssum += __shfl_xor(ssum, off);
        pattn[h][k] = e / ssum;
    }
    load16g(Wq + n*64 + c0, &ws[n*LDSW + c0]);
    __syncthreads();

    // ---- Phase 3: q = x @ Wq (thread keeps exactly its head's 16 cols in regs) ----
    float qr[16];
    #pragma unroll
    for (int j = 0; j < 16; ++j) qr[j] = 0.f;
    mm_row16(&xs[n*LDSW], &ws[c0], qr);
    __syncthreads();

    // ---- Phase 4: load Wk ----
    load16g(Wk + n*64 + c0, &ws[n*LDSW + c0]);
    __syncthreads();

    // ---- Phase 5: k = x @ Wk -> ksh (fp32) ----
    {
        float acc[16];
        #pragma unroll
        for (int j = 0; j < 16; ++j) acc[j] = 0.f;
        mm_row16(&xs[n*LDSW], &ws[c0], acc);
        #pragma unroll
        for (int j = 0; j < 16; j += 4) {
            float4 o; o.x = acc[j]; o.y = acc[j+1]; o.z = acc[j+2]; o.w = acc[j+3];
            *(float4*)&ksh[n*64 + c0 + j] = o;
        }
    }
    __syncthreads();

    // ---- Phase 6: load E^T (E = embeds[id].reshape(64,64); v = x @ E^T) ----
    {
        const float* ge = embeds + (size_t)(*embed_id)*4096 + n*64 + c0;
        float tv[16];
        load16g(ge, tv);
        #pragma unroll
        for (int j = 0; j < 16; ++j) ws[(c0+j)*LDSW + n] = tv[j];
    }
    __syncthreads();

    // ---- Phase 7: v = x @ E^T + s64 -> vsh (bf16) ----
    {
        float acc[16];
        #pragma unroll
        for (int j = 0; j < 16; ++j) acc[j] = s64[c0+j];
        mm_row16(&xs[n*LDSW], &ws[c0], acc);
        u32 p[8];
        #pragma unroll
        for (int j = 0; j < 8; ++j) p[j] = (u32)f2bf(acc[2*j]) | ((u32)f2bf(acc[2*j+1]) << 16);
        uint4* dst = (uint4*)&vsh[n*64 + c0];
        uint4 o0; o0.x=p[0]; o0.y=p[1]; o0.z=p[2]; o0.w=p[3];
        uint4 o1; o1.x=p[4]; o1.y=p[5]; o1.z=p[6]; o1.w=p[7];
        dst[0] = o0; dst[1] = o1;
    }
    __syncthreads();

    // ---- Phase 8: load out_W; fused attention row (thread owns row n, head hq) ----
    load16g(oW + n*64 + c0, &ws[n*LDSW + c0]);

    float g;
    { float gt = gate[hq]; g = 1.f / (1.f + __expf(-gt)); }

    float lg[64];
    #pragma unroll
    for (int k = 0; k < 64; ++k) {
        const float* kr = &ksh[k*64 + c0];
        float s = 0.f;
        #pragma unroll
        for (int j = 0; j < 16; j += 4) {
            float4 kv = *(const float4*)&kr[j];
            s = fmaf(qr[j+0], kv.x, s);
            s = fmaf(qr[j+1], kv.y, s);
            s = fmaf(qr[j+2], kv.z, s);
            s = fmaf(qr[j+3], kv.w, s);
        }
        lg[k] = s * 0.25f;   // 1/sqrt(dh=16)
    }
    float m = lg[0];
    #pragma unroll
    for (int k = 1; k < 64; ++k) m = fmaxf(m, lg[k]);
    float l = 0.f;
    #pragma unroll
    for (int k = 0; k < 64; ++k) { float e = __expf(lg[k] - m); lg[k] = e; l += e; }

    const float c1 = (1.f - g) / l;
    float oacc[16];
    #pragma unroll
    for (int j = 0; j < 16; ++j) oacc[j] = 0.f;
    float tot = 0.f;
    #pragma unroll
    for (int k = 0; k < 64; ++k) {
        float a = fmaf(c1, lg[k], g * pattn[hq][k]);  // mixed, pre-renorm
        tot += a;
        const uint4* vr = (const uint4*)&vsh[k*64 + c0];
        uint4 va = vr[0], vb = vr[1];
        u32 wv[8] = {va.x,va.y,va.z,va.w,vb.x,vb.y,vb.z,vb.w};
        #pragma unroll
        for (int j = 0; j < 8; ++j) {
            oacc[2*j]   = fmaf(a, bflo(wv[j]), oacc[2*j]);
            oacc[2*j+1] = fmaf(a, bfhi(wv[j]), oacc[2*j+1]);
        }
    }
    const float inv = 1.f / tot;   // exact renormalization (sum ~ 1)

    // write context into xs (x no longer needed)
    #pragma unroll
    for (int j = 0; j < 16; j += 4) {
        float4 cv; cv.x = oacc[j]*inv; cv.y = oacc[j+1]*inv; cv.z = oacc[j+2]*inv; cv.w = oacc[j+3]*inv;
        *(float4*)&xs[n*LDSW + c0 + j] = cv;
    }
    __syncthreads();

    // ---- Phase 9: out = ctx @ out_W + out_b; store fp32 ----
    {
        float acc[16];
        #pragma unroll
        for (int j = 0; j < 16; ++j) acc[j] = ob[c0+j];
        mm_row16(&xs[n*LDSW], &ws[c0], acc);
        float4* go = (float4*)(out + ((size_t)b*64 + n)*64 + c0);
        #pragma unroll
        for (int j = 0; j < 4; ++j) {
            float4 o; o.x = acc[4*j]; o.y = acc[4*j+1]; o.z = acc[4*j+2]; o.w = acc[4*j+3];
            go[j] = o;
        }
    }
}

extern "C" void kernel_launch(void* const* d_in, const int* in_sizes, int n_in,
                              void* d_out, int out_size, void* d_ws, size_t ws_size,
                              hipStream_t stream) {
    const int B = in_sizes[0] / (64 * 64);  // 2048
    attn_fused_kernel<<<B, 256, 0, stream>>>(
        (const float*)d_in[0],  (const float*)d_in[1],  (const float*)d_in[2],  (const int*)d_in[3],
        (const float*)d_in[4],  (const float*)d_in[5],  (const float*)d_in[6],  (const float*)d_in[7],
        (const float*)d_in[8],  (const float*)d_in[9],  (const float*)d_in[10], (const float*)d_in[11],
        (const float*)d_in[12], (const float*)d_in[13], (const float*)d_in[14], (const float*)d_in[15],
        (const float*)d_in[16], (const float*)d_in[17], (float*)d_out);
}